// Round 7
// baseline (681.371 us; speedup 1.0000x reference)
//
#include <hip/hip_runtime.h>
#include <hip/hip_fp16.h>
#include <math.h>

#define N_NODES  50000
#define N_EDGES  800000
#define IN_DIM   64
#define HID_DIM  64
#define N_CLS    10
#define ZROW     50000           // zero-row index for pad gathers
#define GRID     512
#define NTHR     256
#define GTH      (GRID * NTHR)   // 131072

// software grid barrier: per-phase counter, device-scope semantics.
// Counters are zeroed by a hipMemsetAsync in kernel_launch (same stream /
// same captured graph) -- NEVER rely on workspace initial contents (re-poison).
// Co-residency: launch_bounds(256,4) -> 4 blocks/CU capacity (1024) >= GRID=512.
__device__ __forceinline__ void gbar(int* cnt) {
    __threadfence();                               // release my writes (agent scope)
    __syncthreads();                               // whole block done + fenced
    if (threadIdx.x == 0) {
        __hip_atomic_fetch_add(cnt, 1, __ATOMIC_ACQ_REL, __HIP_MEMORY_SCOPE_AGENT);
        while (__hip_atomic_load(cnt, __ATOMIC_ACQUIRE, __HIP_MEMORY_SCOPE_AGENT) < GRID)
            __builtin_amdgcn_s_sleep(1);
    }
    __syncthreads();
}

// inclusive wave scan (64 lanes)
__device__ __forceinline__ int wscan_incl(int v, int lane) {
#pragma unroll
    for (int k = 1; k < 64; k <<= 1) {
        int u = __shfl_up(v, k, 64);
        if (lane >= k) v += u;
    }
    return v;
}

// unpack 8 fp16 (carried in a float4) and accumulate into two float4
__device__ __forceinline__ void h8_acc(float4 raw, float4& a, float4& b) {
    union { float4 f; __half2 h[4]; } u;
    u.f = raw;
    float2 p0 = __half22float2(u.h[0]);
    float2 p1 = __half22float2(u.h[1]);
    float2 p2 = __half22float2(u.h[2]);
    float2 p3 = __half22float2(u.h[3]);
    a.x += p0.x; a.y += p0.y; a.z += p1.x; a.w += p1.y;
    b.x += p2.x; b.y += p2.y; b.z += p3.x; b.w += p3.y;
}

__global__ __launch_bounds__(NTHR, 4) void mega(const float* __restrict__ x,
                                                const int* __restrict__ ei,
                                                const float* __restrict__ W1,
                                                const float* __restrict__ b1,
                                                const float* __restrict__ W2,
                                                const float* __restrict__ b2,
                                                float* __restrict__ out,
                                                int* __restrict__ ws) {
    // ---- workspace layout (ints), all 16B-aligned ----
    int*    bar    = ws;                     // 64 ints (barrier counters 0..5; memset to 0 at launch)
    int*    deg    = bar  + 64;              // 50176
    int*    cur    = deg  + 50176;           // 50176
    int*    off    = cur  + 50176;           // 50176
    int*    nendA  = off  + 50176;           // 50176
    float*  dinv   = (float*)(nendA + 50176);// 50176
    int*    galloc = (int*)(dinv + 50176);   // 16 (slot 0 used; init in P1)
    int*    csr    = galloc + 16;            // 1,048,576 (4 MB; need <= 950k)
    float2* xlh    = (float2*)(csr + 1048576);                       // (N+1) x 16 float2
    __half2* hlh2  = (__half2*)(xlh + (size_t)(N_NODES + 1) * 16);   // (N+1) x 8 half2

    const int* srcA = ei;                 // edge_index[0]
    const int* dstA = ei + N_EDGES;       // edge_index[1]

    int t  = threadIdx.x;
    int b  = blockIdx.x;
    int gt = b * NTHR + t;

    __shared__ __align__(16) char smemraw[20992];   // union: P5 gemm 20.5KB / P6 sW2 2.8KB

    // ================= P1: clear deg, init allocator, zero pad rows =================
    for (int i = gt; i < 50176; i += GTH) deg[i] = 0;
    if (gt == 0) galloc[0] = 0;
    if (gt >= 32 && gt < 48) xlh[(size_t)ZROW * 16 + (gt - 32)] = make_float2(0.f, 0.f);
    if (gt >= 48 && gt < 56) hlh2[(size_t)ZROW * 8 + (gt - 48)] = __floats2half2_rn(0.f, 0.f);
    gbar(&bar[0]);

    // ================= P2: degree histogram (800k device atomics over 50k ctrs) =====
    for (int i = gt; i < N_EDGES; i += GTH)
        atomicAdd(&deg[dstA[i]], 1);
    gbar(&bar[1]);

    // ================= P3: csr range alloc + off/nend/dinv/cur + pad prefill ========
    // 2 waves/block, each owns a 49-node chunk: wave-scan of padded degrees,
    // one global atomicAdd reserves the chunk's csr range (order irrelevant).
    if (t < 128) {
        int w = t >> 6, lane = t & 63;
        int chunk = b * 2 + w;               // 0..1023; covers 50176 >= 50000 nodes
        int node = chunk * 49 + lane;
        int dv = 0;
        if (lane < 49 && node < N_NODES) dv = deg[node];
        int padded = (lane < 49) ? ((dv + 3) & ~3) : 0;
        int incl = wscan_incl(padded, lane);
        int excl = incl - padded;
        int total = __shfl(incl, 63, 64);    // lanes >= 49 contribute 0
        int basev = 0;
        if (lane == 0) basev = atomicAdd(galloc, total);
        basev = __shfl(basev, 0, 64);
        if (lane < 49 && node < N_NODES) {
            int o = basev + excl;
            off[node]   = o;
            nendA[node] = o + padded;
            cur[node]   = o;
            dinv[node]  = rsqrtf((float)(dv + 1));     // +1 self-loop
            for (int k2 = dv; k2 < padded; ++k2) csr[o + k2] = ZROW;  // <=3 pads
        }
    }
    gbar(&bar[2]);

    // ================= P4: edge scatter (atomic-return cursor) ======================
    for (int i = gt; i < N_EDGES; i += GTH) {
        int d = dstA[i];
        int slot = atomicAdd(&cur[d], 1);
        csr[slot] = srcA[i];
    }
    gbar(&bar[3]);

    // ================= P5: xl' = fp16((x @ W1) * dinv), 16-row tiles ================
    {
        float4* sW4 = (float4*)smemraw;              // 1024 float4 = 16 KB
        float4* sx4 = (float4*)(smemraw + 16384);    // 256 float4 = 4 KB
        const float4* W4 = (const float4*)W1;
        sW4[t]       = W4[t];
        sW4[t + 256] = W4[t + 256];
        sW4[t + 512] = W4[t + 512];
        sW4[t + 768] = W4[t + 768];
        const float4* x4 = (const float4*)x;
        int r = t >> 4, cq = t & 15;
        for (int vb = b; vb < 3125; vb += GRID) {
            __syncthreads();                         // sW4 ready / sx4 safe to overwrite
            sx4[t] = x4[(size_t)vb * 256 + t];       // 16 rows x 16 quads, coalesced
            __syncthreads();
            const float4* sxr = &sx4[r * 16];
            float ax = 0.f, ay = 0.f, az = 0.f, aw = 0.f;
#pragma unroll
            for (int k4 = 0; k4 < 16; ++k4) {
                float4 xv = sxr[k4];
                float4 w0 = sW4[(k4 * 4 + 0) * 16 + cq];
                float4 w1 = sW4[(k4 * 4 + 1) * 16 + cq];
                float4 w2 = sW4[(k4 * 4 + 2) * 16 + cq];
                float4 w3 = sW4[(k4 * 4 + 3) * 16 + cq];
                ax += xv.x * w0.x + xv.y * w1.x + xv.z * w2.x + xv.w * w3.x;
                ay += xv.x * w0.y + xv.y * w1.y + xv.z * w2.y + xv.w * w3.y;
                az += xv.x * w0.z + xv.y * w1.z + xv.z * w2.z + xv.w * w3.z;
                aw += xv.x * w0.w + xv.y * w1.w + xv.z * w2.w + xv.w * w3.w;
            }
            int row = vb * 16 + r;
            float dvv = dinv[row];
            union { __half2 h[2]; float2 f; } u;
            u.h[0] = __floats2half2_rn(ax * dvv, ay * dvv);
            u.h[1] = __floats2half2_rn(az * dvv, aw * dvv);
            xlh[(size_t)row * 16 + cq] = u.f;
        }
    }
    gbar(&bar[4]);

    // ================= P6: layer-1 gather + relu + (h@W2)*dinv -> fp16 hl' ==========
    {
        float* sW2 = (float*)smemraw;                // [64][11] padded
        for (int i = t; i < HID_DIM * N_CLS; i += NTHR) {
            int rr = i / N_CLS, cc = i - rr * N_CLS;
            sW2[rr * (N_CLS + 1) + cc] = W2[i];
        }
        __syncthreads();
        const float4* xlph = (const float4*)xlh;
        int d8 = t & 7;
        for (int vb = b; vb < 1568; vb += GRID) {
            int node = vb * 32 + (t >> 3);           // 1568*32 = 50176
            bool valid = node < N_NODES;
            int nd = valid ? node : ZROW;
            int beg = 0, end = 0;
            if (valid) { beg = off[node]; end = nendA[node]; }
            float4 aA = make_float4(0.f, 0.f, 0.f, 0.f);
            float4 aB = make_float4(0.f, 0.f, 0.f, 0.f);
            h8_acc(xlph[(size_t)nd * 8 + d8], aA, aB);   // self-loop
            int j = beg;
            for (; j + 8 <= end; j += 8) {
                int4 c0 = *(const int4*)(csr + j);
                int4 c1 = *(const int4*)(csr + j + 4);
                float4 r0 = xlph[(size_t)c0.x * 8 + d8];
                float4 r1 = xlph[(size_t)c0.y * 8 + d8];
                float4 r2 = xlph[(size_t)c0.z * 8 + d8];
                float4 r3 = xlph[(size_t)c0.w * 8 + d8];
                float4 r4 = xlph[(size_t)c1.x * 8 + d8];
                float4 r5 = xlph[(size_t)c1.y * 8 + d8];
                float4 r6 = xlph[(size_t)c1.z * 8 + d8];
                float4 r7 = xlph[(size_t)c1.w * 8 + d8];
                h8_acc(r0, aA, aB); h8_acc(r1, aA, aB);
                h8_acc(r2, aA, aB); h8_acc(r3, aA, aB);
                h8_acc(r4, aA, aB); h8_acc(r5, aA, aB);
                h8_acc(r6, aA, aB); h8_acc(r7, aA, aB);
            }
            if (j < end) {                           // one padded 4-block
                int4 c0 = *(const int4*)(csr + j);
                float4 r0 = xlph[(size_t)c0.x * 8 + d8];
                float4 r1 = xlph[(size_t)c0.y * 8 + d8];
                float4 r2 = xlph[(size_t)c0.z * 8 + d8];
                float4 r3 = xlph[(size_t)c0.w * 8 + d8];
                h8_acc(r0, aA, aB); h8_acc(r1, aA, aB);
                h8_acc(r2, aA, aB); h8_acc(r3, aA, aB);
            }
            float dvv = valid ? dinv[node] : 0.0f;
            float4 b1a = ((const float4*)b1)[d8 * 2];
            float4 b1b = ((const float4*)b1)[d8 * 2 + 1];
            float h0 = fmaxf(dvv * aA.x + b1a.x, 0.0f);
            float h1 = fmaxf(dvv * aA.y + b1a.y, 0.0f);
            float h2 = fmaxf(dvv * aA.z + b1a.z, 0.0f);
            float h3 = fmaxf(dvv * aA.w + b1a.w, 0.0f);
            float h4 = fmaxf(dvv * aB.x + b1b.x, 0.0f);
            float h5 = fmaxf(dvv * aB.y + b1b.y, 0.0f);
            float h6 = fmaxf(dvv * aB.z + b1b.z, 0.0f);
            float h7 = fmaxf(dvv * aB.w + b1b.w, 0.0f);
            float p[N_CLS];
            int k0 = d8 * 8;
#pragma unroll
            for (int c = 0; c < N_CLS; ++c)
                p[c] = h0 * sW2[(k0 + 0) * (N_CLS + 1) + c] + h1 * sW2[(k0 + 1) * (N_CLS + 1) + c]
                     + h2 * sW2[(k0 + 2) * (N_CLS + 1) + c] + h3 * sW2[(k0 + 3) * (N_CLS + 1) + c]
                     + h4 * sW2[(k0 + 4) * (N_CLS + 1) + c] + h5 * sW2[(k0 + 5) * (N_CLS + 1) + c]
                     + h6 * sW2[(k0 + 6) * (N_CLS + 1) + c] + h7 * sW2[(k0 + 7) * (N_CLS + 1) + c];
#pragma unroll
            for (int k = 1; k < 8; k <<= 1) {
#pragma unroll
                for (int c = 0; c < N_CLS; ++c) p[c] += __shfl_xor(p[c], k, 64);
            }
            if (valid) {
                float va = 0.f, vb2 = 0.f;
                int c0i = d8 * 2, c1i = d8 * 2 + 1;
#pragma unroll
                for (int c = 0; c < N_CLS; ++c) {
                    va  = (c0i == c) ? p[c] : va;
                    vb2 = (c1i == c) ? p[c] : vb2;
                }
                hlh2[(size_t)node * 8 + d8] = __floats2half2_rn(va * dvv, vb2 * dvv);
            }
        }
    }
    gbar(&bar[5]);

    // ================= P7: layer-2 gather + b2 + log_softmax ========================
    {
        float2* out2 = (float2*)out;
        int d8 = t & 7;
        for (int vb = b; vb < 1568; vb += GRID) {
            int node = vb * 32 + (t >> 3);
            bool valid = node < N_NODES;
            int nd = valid ? node : ZROW;
            int beg = 0, end = 0;
            if (valid) { beg = off[node]; end = nendA[node]; }
            float2 self = __half22float2(hlh2[(size_t)nd * 8 + d8]);
            float accx = self.x, accy = self.y;
            int j = beg;
            for (; j + 8 <= end; j += 8) {
                int4 c0 = *(const int4*)(csr + j);
                int4 c1 = *(const int4*)(csr + j + 4);
                float2 f0 = __half22float2(hlh2[(size_t)c0.x * 8 + d8]);
                float2 f1 = __half22float2(hlh2[(size_t)c0.y * 8 + d8]);
                float2 f2 = __half22float2(hlh2[(size_t)c0.z * 8 + d8]);
                float2 f3 = __half22float2(hlh2[(size_t)c0.w * 8 + d8]);
                float2 f4 = __half22float2(hlh2[(size_t)c1.x * 8 + d8]);
                float2 f5 = __half22float2(hlh2[(size_t)c1.y * 8 + d8]);
                float2 f6 = __half22float2(hlh2[(size_t)c1.z * 8 + d8]);
                float2 f7 = __half22float2(hlh2[(size_t)c1.w * 8 + d8]);
                accx += ((f0.x + f1.x) + (f2.x + f3.x)) + ((f4.x + f5.x) + (f6.x + f7.x));
                accy += ((f0.y + f1.y) + (f2.y + f3.y)) + ((f4.y + f5.y) + (f6.y + f7.y));
            }
            if (j < end) {
                int4 c0 = *(const int4*)(csr + j);
                float2 f0 = __half22float2(hlh2[(size_t)c0.x * 8 + d8]);
                float2 f1 = __half22float2(hlh2[(size_t)c0.y * 8 + d8]);
                float2 f2 = __half22float2(hlh2[(size_t)c0.z * 8 + d8]);
                float2 f3 = __half22float2(hlh2[(size_t)c0.w * 8 + d8]);
                accx += (f0.x + f1.x) + (f2.x + f3.x);
                accy += (f0.y + f1.y) + (f2.y + f3.y);
            }
            bool act = valid && (d8 < 5);
            float dvv = valid ? dinv[node] : 0.f;
            float2 bb = make_float2(0.f, 0.f);
            if (d8 < 5) bb = ((const float2*)b2)[d8];
            float vx = act ? dvv * accx + bb.x : -INFINITY;
            float vy = act ? dvv * accy + bb.y : -INFINITY;
            float m = fmaxf(vx, vy);
#pragma unroll
            for (int k = 1; k < 8; k <<= 1) m = fmaxf(m, __shfl_xor(m, k, 64));
            float ex = act ? (expf(vx - m) + expf(vy - m)) : 0.f;
#pragma unroll
            for (int k = 1; k < 8; k <<= 1) ex += __shfl_xor(ex, k, 64);
            if (act) {
                float l = m + logf(ex);
                out2[(size_t)node * 5 + d8] = make_float2(vx - l, vy - l);
            }
        }
    }
}

extern "C" void kernel_launch(void* const* d_in, const int* in_sizes, int n_in,
                              void* d_out, int out_size, void* d_ws, size_t ws_size,
                              hipStream_t stream) {
    const float* x  = (const float*)d_in[0];
    const int*   ei = (const int*)d_in[1];
    const float* W1 = (const float*)d_in[2];
    const float* b1 = (const float*)d_in[3];
    const float* W2 = (const float*)d_in[4];
    const float* b2 = (const float*)d_in[5];
    float* out = (float*)d_out;
    int*   ws  = (int*)d_ws;

    // Zero the grid-barrier counters (and padding) -- stream-ordered, replayed by
    // the captured graph each iteration. Do NOT rely on workspace initial contents.
    hipMemsetAsync(d_ws, 0, 256, stream);
    mega<<<GRID, NTHR, 0, stream>>>(x, ei, W1, b1, W2, b2, out, ws);
    (void)in_sizes; (void)n_in; (void)out_size; (void)ws_size;
}